// Round 5
// baseline (215.466 us; speedup 1.0000x reference)
//
#include <hip/hip_runtime.h>

// StrictLowerTriQSM: f_{i+1} = a_i @ f_i + outer(q_i, x_i), y_i = p_i @ f_i
// N=500000, M=8, K=16. Blocked associative scan, 4 kernels.
// Round 5: triple-buffered staging (2 stages in flight, counted vmcnt),
// k3 at 2 chunks/wave (4 waves/SIMD, mirrored upper lanes), xk_eff predicate
// fold in k1, register-lean f-init in k3.

#define NTOT 500000
#define CHUNK 64
#define NCHUNK 8192            // 8192*64 = 524288 >= 500000
#define G 4                    // elements per staging group
#define NGPC 16                // groups per chunk
#define GRPSZ 64
#define NGRP 128               // 8192/64
#define CLAMPI 499996          // NTOT - G

// workspace float offsets (COLUMN-major tiles: [c][col][row])
#define OFF_AGGA  0u           // NCHUNK*64  = 524288
#define OFF_AGGB  524288u      // NCHUNK*128 = 1048576
#define OFF_GAGA  1572864u     // NGRP*64    = 8192
#define OFF_GAGB  1581056u     // NGRP*128   = 16384

#define AS1(p) ((const __attribute__((address_space(1))) void*)(p))
#define AS3(p) ((__attribute__((address_space(3))) void*)(p))
#define GLOAD_LDS16(gp, lp) __builtin_amdgcn_global_load_lds(AS1(gp), AS3(lp), 16, 0, 0)
#define GLOAD_LDS4(gp, lp)  __builtin_amdgcn_global_load_lds(AS1(gp), AS3(lp), 4, 0, 0)
#define WAIT_VM(n) asm volatile("s_waitcnt vmcnt(" #n ")" ::: "memory")

static __device__ __forceinline__ int iminc(int a, int b) { return a < b ? a : b; }

// ---------------- Phase 1: per-chunk aggregates (A_blk, B_blk) -------------
// 2 chunks per wave: lanes [0..31] -> chunk 2w, [32..63] -> chunk 2w+1.
// Within a 32-lane half: ll<16 = B columns, 16<=ll<24 = A columns.
// Triple-buffered per-wave LDS: 3 x [A 2x256 | q 64 | x 128] = 3*704 floats.
__global__ __launch_bounds__(256, 4) void k1_aggregate(
    const float* __restrict__ q, const float* __restrict__ a,
    const float* __restrict__ x, float* __restrict__ ws)
{
  __shared__ float sm[4 * 3 * 704];   // 33792 B
  const int wv   = (int)(threadIdx.x >> 6);
  const int wave = blockIdx.x * 4 + wv;          // 0..4095
  const int lane = (int)(threadIdx.x & 63);
  const int sub  = lane >> 5;                    // which chunk of the pair
  const int ll   = lane & 31;
  const int c    = wave * 2 + sub;               // this lane's chunk
  const bool isB = ll < 16;
  const bool isA = (ll >= 16) && (ll < 24);
  const int bcol = ll & 15;
  const int acol = (ll - 16) & 7;

  const int c0 = wave * 2, c1 = c0 + 1;
  float* b0 = sm + wv * 2112;
  float* b1 = b0 + 704;
  float* b2 = b0 + 1408;

  float v[8];
#pragma unroll
  for (int m = 0; m < 8; ++m) v[m] = 0.f;
  if (isA) v[acol] = 1.f;                        // A starts as identity

  int cnt = NTOT - c * CHUNK;
  cnt = cnt < 0 ? 0 : (cnt > CHUNK ? CHUNK : cnt);

  auto stage = [&](int g, float* lb) {
    const int e0 = iminc(c0 * CHUNK + g * G, CLAMPI);
    const int e1 = iminc(c1 * CHUNK + g * G, CLAMPI);
    GLOAD_LDS16(a + (size_t)e0 * 64u + lane * 4, lb);        // chunk0 A (256 f)
    GLOAD_LDS16(a + (size_t)e1 * 64u + lane * 4, lb + 256);  // chunk1 A
    GLOAD_LDS4(q + (size_t)(lane < 32 ? e0 : e1) * 8u + ll, lb + 512); // q (64 f)
    GLOAD_LDS4(x + (size_t)e0 * 16u + lane, lb + 576);       // chunk0 x (64 f)
    GLOAD_LDS4(x + (size_t)e1 * 16u + lane, lb + 640);       // chunk1 x
  };

  stage(0, b0);
  stage(1, b1);
#pragma unroll 1
  for (int g = 0; g < NGPC; ++g) {
    float* lb = b0;
    if (g + 2 < NGPC) {
      stage(g + 2, b2);
      WAIT_VM(10);                 // 2 stages (10 loads) stay in flight
    } else if (g + 1 < NGPC) {
      WAIT_VM(5);
    } else {
      WAIT_VM(0);
    }
#pragma unroll 1
    for (int e = 0; e < G; ++e) {
      const int eg = g * G + e;
      if (eg < cnt) {
        const float* ae = lb + sub * 256 + e * 64;   // row-major a[m][t]
        const float xk  = lb[576 + sub * 64 + e * 16 + bcol];
        const float xke = isB ? xk : 0.f;
        const float* qe = lb + 512 + sub * 32 + e * 8;
        float qv[8];
        *(float4*)&qv[0] = *(const float4*)(qe);
        *(float4*)&qv[4] = *(const float4*)(qe + 4);
        float nv[8];
#pragma unroll
        for (int m = 0; m < 8; ++m) {
          float4 r0 = *(const float4*)(ae + m * 8);
          float4 r1 = *(const float4*)(ae + m * 8 + 4);
          float s = qv[m] * xke;
          s += r0.x * v[0] + r0.y * v[1] + r0.z * v[2] + r0.w * v[3]
             + r1.x * v[4] + r1.y * v[5] + r1.z * v[6] + r1.w * v[7];
          nv[m] = s;
        }
#pragma unroll
        for (int m = 0; m < 8; ++m) v[m] = nv[m];
      }
    }
    float* t = b0; b0 = b1; b1 = b2; b2 = t;    // rotate buffers
  }

  if (isB) {
    float* dst = ws + OFF_AGGB + (size_t)c * 128u + (size_t)bcol * 8u;
#pragma unroll
    for (int m = 0; m < 8; ++m) dst[m] = v[m];
  } else if (isA) {
    float* dst = ws + OFF_AGGA + (size_t)c * 64u + (size_t)acol * 8u;
#pragma unroll
    for (int m = 0; m < 8; ++m) dst[m] = v[m];
  }
}

// ---------- Phase 2a: serial scan inside each group of 64 chunks -----------
// A-tiles staged to LDS up front (pipelined global_load_lds); B operands
// software-prefetched one combine ahead. IN-PLACE: slot <- exclusive prefix.
__global__ __launch_bounds__(64) void k2a_groupscan(float* __restrict__ ws)
{
  __shared__ float sA[GRPSZ * 64];   // 16 KiB
  const int g    = blockIdx.x;
  const int lane = (int)(threadIdx.x & 63);
  const bool isB = lane < 16;
  const bool isA = (lane >= 16) && (lane < 24);
  const int bcol = lane & 15;
  const int acol = (lane - 16) & 7;

#pragma unroll 1
  for (int t = 0; t < 16; ++t)
    GLOAD_LDS16(ws + OFF_AGGA + (size_t)g * (GRPSZ * 64u) + t * 256 + lane * 4,
                sA + t * 256);

  float v[8];
#pragma unroll
  for (int m = 0; m < 8; ++m) v[m] = 0.f;
  if (isA) v[acol] = 1.f;

  // prefetch B of combine 0
  float4 nb0, nb1;
  {
    const float* s = ws + OFF_AGGB + (size_t)(g * GRPSZ) * 128u + (size_t)bcol * 8u;
    nb0 = *(const float4*)s; nb1 = *(const float4*)(s + 4);
  }
  WAIT_VM(0);   // LDS staging complete

#pragma unroll 1
  for (int j = 0; j < GRPSZ; ++j) {
    const int c = g * GRPSZ + j;
    float bB[8] = {nb0.x, nb0.y, nb0.z, nb0.w, nb1.x, nb1.y, nb1.z, nb1.w};
    if (j + 1 < GRPSZ) {
      const float* s = ws + OFF_AGGB + (size_t)(c + 1) * 128u + (size_t)bcol * 8u;
      nb0 = *(const float4*)s; nb1 = *(const float4*)(s + 4);
    }
    // overwrite slot with the exclusive prefix (= current run)
    if (isB) {
      float* dst = ws + OFF_AGGB + (size_t)c * 128u + (size_t)bcol * 8u;
#pragma unroll
      for (int m = 0; m < 8; ++m) dst[m] = v[m];
    } else if (isA) {
      float* dst = ws + OFF_AGGA + (size_t)c * 64u + (size_t)acol * 8u;
#pragma unroll
      for (int m = 0; m < 8; ++m) dst[m] = v[m];
    }
    // run = agg_c ∘ run : (Ac@Arun, Ac@Brun + Bc). sA tile is column-major.
    const float* Aj = sA + j * 64;
    float nv[8];
#pragma unroll
    for (int m = 0; m < 8; ++m) nv[m] = 0.f;
#pragma unroll
    for (int t = 0; t < 8; ++t) {
      float4 col0 = *(const float4*)(Aj + t * 8);
      float4 col1 = *(const float4*)(Aj + t * 8 + 4);
      nv[0] += col0.x * v[t]; nv[1] += col0.y * v[t];
      nv[2] += col0.z * v[t]; nv[3] += col0.w * v[t];
      nv[4] += col1.x * v[t]; nv[5] += col1.y * v[t];
      nv[6] += col1.z * v[t]; nv[7] += col1.w * v[t];
    }
    if (isB) {
#pragma unroll
      for (int m = 0; m < 8; ++m) nv[m] += bB[m];
    }
#pragma unroll
    for (int m = 0; m < 8; ++m) v[m] = nv[m];
  }

  if (isB) {
    float* dst = ws + OFF_GAGB + (size_t)g * 128u + (size_t)bcol * 8u;
#pragma unroll
    for (int m = 0; m < 8; ++m) dst[m] = v[m];
  } else if (isA) {
    float* dst = ws + OFF_GAGA + (size_t)g * 64u + (size_t)acol * 8u;
#pragma unroll
    for (int m = 0; m < 8; ++m) dst[m] = v[m];
  }
}

// ---------- Phase 2b: single-wave scan over the NGRP group aggregates ------
// GAGA staged to LDS; B prefetched. IN-PLACE on GAGB: slot <- exclusive B.
__global__ __launch_bounds__(64) void k2b_topscan(float* __restrict__ ws)
{
  __shared__ float sA[NGRP * 64];    // 32 KiB
  const int lane = (int)(threadIdx.x & 63);
  const bool isB = lane < 16;
  const bool isA = (lane >= 16) && (lane < 24);
  const int bcol = lane & 15;
  const int acol = (lane - 16) & 7;

#pragma unroll 1
  for (int t = 0; t < 32; ++t)
    GLOAD_LDS16(ws + OFF_GAGA + t * 256 + lane * 4, sA + t * 256);

  float v[8];
#pragma unroll
  for (int m = 0; m < 8; ++m) v[m] = 0.f;
  if (isA) v[acol] = 1.f;

  float4 nb0, nb1;
  {
    const float* s = ws + OFF_GAGB + (size_t)bcol * 8u;
    nb0 = *(const float4*)s; nb1 = *(const float4*)(s + 4);
  }
  WAIT_VM(0);

#pragma unroll 1
  for (int j = 0; j < NGRP; ++j) {
    float bB[8] = {nb0.x, nb0.y, nb0.z, nb0.w, nb1.x, nb1.y, nb1.z, nb1.w};
    if (j + 1 < NGRP) {
      const float* s = ws + OFF_GAGB + (size_t)(j + 1) * 128u + (size_t)bcol * 8u;
      nb0 = *(const float4*)s; nb1 = *(const float4*)(s + 4);
    }
    if (isB) {
      float* dst = ws + OFF_GAGB + (size_t)j * 128u + (size_t)bcol * 8u;
#pragma unroll
      for (int m = 0; m < 8; ++m) dst[m] = v[m];
    }
    const float* Aj = sA + j * 64;
    float nv[8];
#pragma unroll
    for (int m = 0; m < 8; ++m) nv[m] = 0.f;
#pragma unroll
    for (int t = 0; t < 8; ++t) {
      float4 col0 = *(const float4*)(Aj + t * 8);
      float4 col1 = *(const float4*)(Aj + t * 8 + 4);
      nv[0] += col0.x * v[t]; nv[1] += col0.y * v[t];
      nv[2] += col0.z * v[t]; nv[3] += col0.w * v[t];
      nv[4] += col1.x * v[t]; nv[5] += col1.y * v[t];
      nv[6] += col1.z * v[t]; nv[7] += col1.w * v[t];
    }
    if (isB) {
#pragma unroll
      for (int m = 0; m < 8; ++m) nv[m] += bB[m];
    }
#pragma unroll
    for (int m = 0; m < 8; ++m) v[m] = nv[m];
  }
}

// ---------- Phase 3: replay each chunk from its carry, emit y --------------
// 2 chunks per wave: sub=(lane>>4)&1 picks the chunk, k=lane&15 the f-column.
// Lanes 32..63 mirror lanes 0..31 (same compute, no store) — SIMD-free.
// Triple-buffered per-wave LDS: 3 x [A 2x260 | q 64 | p 64 | x 128] = 3*784.
#define K3_BQ 520
#define K3_BP 584
#define K3_BX 648
#define K3_BUF 784
__global__ __launch_bounds__(256, 4) void k3_output(
    const float* __restrict__ p, const float* __restrict__ q,
    const float* __restrict__ a, const float* __restrict__ x,
    const float* __restrict__ ws, float* __restrict__ out)
{
  __shared__ float sm3[4 * 3 * K3_BUF];   // 37632 B
  const int wv   = (int)(threadIdx.x >> 6);
  const int wave = blockIdx.x * 4 + wv;          // 0..4095
  const int lane = (int)(threadIdx.x & 63);
  const int sub  = (lane >> 4) & 1;              // chunk 0/1 of the pair
  const int k    = lane & 15;                    // f column
  const bool active = lane < 32;
  const int c    = wave * 2 + sub;
  const int grp  = c >> 6;                       // GRPSZ = 64

  const int c0 = wave * 2, c1 = c0 + 1;
  float* b0 = sm3 + wv * (3 * K3_BUF);
  float* b1 = b0 + K3_BUF;
  float* b2 = b0 + 2 * K3_BUF;

  auto stage = [&](int g, float* lb) {
    const int e0 = iminc(c0 * CHUNK + g * G, CLAMPI);
    const int e1 = iminc(c1 * CHUNK + g * G, CLAMPI);
    GLOAD_LDS16(a + (size_t)e0 * 64u + lane * 4, lb);
    GLOAD_LDS16(a + (size_t)e1 * 64u + lane * 4, lb + 260);
    GLOAD_LDS4(q + (size_t)(lane < 32 ? e0 : e1) * 8u + (lane & 31), lb + K3_BQ);
    GLOAD_LDS4(p + (size_t)(lane < 32 ? e0 : e1) * 8u + (lane & 31), lb + K3_BP);
    GLOAD_LDS4(x + (size_t)e0 * 16u + lane, lb + K3_BX);
    GLOAD_LDS4(x + (size_t)e1 * 16u + lane, lb + K3_BX + 64);
  };

  stage(0, b0);   // issue first, hide under the f-init below
  stage(1, b1);

  // init f column k = prefA_c @ grpB[:,k] + prefB_c[:,k]  (ws is col-major,
  // streamed column-by-column to stay register-lean)
  const float* __restrict__ pA  = ws + OFF_AGGA + (size_t)c * 64u;
  const float* __restrict__ gBp = ws + OFF_GAGB + (size_t)grp * 128u + (size_t)k * 8u;
  const float* __restrict__ lBp = ws + OFF_AGGB + (size_t)c * 128u + (size_t)k * 8u;
  float gcol[8];
#pragma unroll
  for (int t = 0; t < 8; ++t) gcol[t] = gBp[t];
  float f[8];
#pragma unroll
  for (int m = 0; m < 8; ++m) f[m] = lBp[m];
#pragma unroll
  for (int t = 0; t < 8; ++t) {
    float4 col0 = *(const float4*)(pA + t * 8);
    float4 col1 = *(const float4*)(pA + t * 8 + 4);
    const float gt = gcol[t];
    f[0] += col0.x * gt; f[1] += col0.y * gt;
    f[2] += col0.z * gt; f[3] += col0.w * gt;
    f[4] += col1.x * gt; f[5] += col1.y * gt;
    f[6] += col1.z * gt; f[7] += col1.w * gt;
  }

  int cnt = NTOT - c * CHUNK;
  cnt = cnt < 0 ? 0 : (cnt > CHUNK ? CHUNK : cnt);

#pragma unroll 1
  for (int g = 0; g < NGPC; ++g) {
    float* lb = b0;
    if (g + 2 < NGPC) {
      stage(g + 2, b2);
      WAIT_VM(12);                 // 2 stages (12 loads) stay in flight
    } else if (g + 1 < NGPC) {
      WAIT_VM(6);
    } else {
      WAIT_VM(0);
    }
#pragma unroll 1
    for (int e = 0; e < G; ++e) {
      const int eg = g * G + e;
      if (eg < cnt) {
        const int i = c * CHUNK + eg;
        const float* ae = lb + sub * 260 + e * 64;           // row-major a
        const float* qe = lb + K3_BQ + sub * 32 + e * 8;
        const float* pe = lb + K3_BP + sub * 32 + e * 8;
        const float xk  = lb[K3_BX + sub * 64 + e * 16 + k];
        float qv[8], pv[8];
        *(float4*)&qv[0] = *(const float4*)(qe);
        *(float4*)&qv[4] = *(const float4*)(qe + 4);
        *(float4*)&pv[0] = *(const float4*)(pe);
        *(float4*)&pv[4] = *(const float4*)(pe + 4);

        float y = 0.f;
#pragma unroll
        for (int m = 0; m < 8; ++m) y += pv[m] * f[m];
        if (active) out[(size_t)i * 16u + k] = y;

        float nf[8];
#pragma unroll
        for (int m = 0; m < 8; ++m) {
          float4 r0 = *(const float4*)(ae + m * 8);
          float4 r1 = *(const float4*)(ae + m * 8 + 4);
          float s = qv[m] * xk;
          s += r0.x * f[0] + r0.y * f[1] + r0.z * f[2] + r0.w * f[3]
             + r1.x * f[4] + r1.y * f[5] + r1.z * f[6] + r1.w * f[7];
          nf[m] = s;
        }
#pragma unroll
        for (int m = 0; m < 8; ++m) f[m] = nf[m];
      }
    }
    float* t = b0; b0 = b1; b1 = b2; b2 = t;    // rotate buffers
  }
}

extern "C" void kernel_launch(void* const* d_in, const int* in_sizes, int n_in,
                              void* d_out, int out_size, void* d_ws, size_t ws_size,
                              hipStream_t stream)
{
  const float* p = (const float*)d_in[0];
  const float* q = (const float*)d_in[1];
  const float* a = (const float*)d_in[2];
  const float* x = (const float*)d_in[3];
  float* out = (float*)d_out;
  float* ws  = (float*)d_ws;

  hipLaunchKernelGGL(k1_aggregate, dim3(NCHUNK / 2 / 4), dim3(256), 0, stream, q, a, x, ws);
  hipLaunchKernelGGL(k2a_groupscan, dim3(NGRP), dim3(64), 0, stream, ws);
  hipLaunchKernelGGL(k2b_topscan, dim3(1), dim3(64), 0, stream, ws);
  hipLaunchKernelGGL(k3_output, dim3(NCHUNK / 2 / 4), dim3(256), 0, stream, p, q, a, x, ws, out);
}

// Round 6
// 197.490 us; speedup vs baseline: 1.0910x; 1.0910x over previous
//
#include <hip/hip_runtime.h>

// StrictLowerTriQSM: f_{i+1} = a_i @ f_i + outer(q_i, x_i), y_i = p_i @ f_i
// N=500000, M=8, K=16. Blocked associative scan, 4 kernels.
// Round 6: 4 chunks/wave in k1 and k3 (16 lanes per chunk) so each LDS
// broadcast read serves 4 chunks; 16B-staggered chunk sub-tiles for
// conflict-free multicast; triple-buffered global_load_lds staging.

#define NTOT 500000
#define CHUNK 64
#define NCHUNK 8192            // 8192*64 = 524288 >= 500000
#define G 4                    // elements per staging group
#define NGPC 16                // groups per chunk
#define GRPSZ 64
#define NGRP 128               // 8192/64
#define CLAMPI 499996          // NTOT - G

// workspace float offsets (COLUMN-major tiles: [c][col][row])
#define OFF_AGGA  0u           // NCHUNK*64  = 524288
#define OFF_AGGB  524288u      // NCHUNK*128 = 1048576
#define OFF_GAGA  1572864u     // NGRP*64    = 8192
#define OFF_GAGB  1581056u     // NGRP*128   = 16384

#define AS1(p) ((const __attribute__((address_space(1))) void*)(p))
#define AS3(p) ((__attribute__((address_space(3))) void*)(p))
#define GLOAD_LDS16(gp, lp) __builtin_amdgcn_global_load_lds(AS1(gp), AS3(lp), 16, 0, 0)
#define GLOAD_LDS4(gp, lp)  __builtin_amdgcn_global_load_lds(AS1(gp), AS3(lp), 4, 0, 0)
#define WAIT_VM(n) asm volatile("s_waitcnt vmcnt(" #n ")" ::: "memory")

static __device__ __forceinline__ int iminc(int a, int b) { return a < b ? a : b; }

// ---------------- Phase 1: per-chunk aggregates (A_blk, B_blk) -------------
// 4 chunks/wave: group g = lane>>4 owns chunk wave*4+g; ll = lane&15.
// Lane ll: B-column ll of its chunk; lanes ll in [8,16) also run the
// A-column (ll-8) matvec, reusing the same A row registers.
// Buffer layout (floats): A: g*260 (stagger 16B); q pairs: 1040 + (g>>1)*68
// + (g&1)*32; x: 1176 + g*80. BUF = 1480.
#define K1_BQ 1040
#define K1_BX 1176
#define K1_BUF 1480
__global__ __launch_bounds__(256, 2) void k1_aggregate(
    const float* __restrict__ q, const float* __restrict__ a,
    const float* __restrict__ x, float* __restrict__ ws)
{
  __shared__ float sm[4 * 3 * K1_BUF];   // 71040 B
  const int wv   = (int)(threadIdx.x >> 6);
  const int wave = blockIdx.x * 4 + wv;          // 0..2047
  const int lane = (int)(threadIdx.x & 63);
  const int g    = lane >> 4;                    // chunk 0..3 of the quad
  const int ll   = lane & 15;
  const int c    = wave * 4 + g;                 // this lane's chunk
  const bool hasA = ll >= 8;
  const int acol = ll & 7;

  const int cb = wave * 4;
  float* b0 = sm + wv * (3 * K1_BUF);
  float* b1 = b0 + K1_BUF;
  float* b2 = b0 + 2 * K1_BUF;

  float vB[8], vA[8];
#pragma unroll
  for (int m = 0; m < 8; ++m) { vB[m] = 0.f; vA[m] = 0.f; }
  if (hasA) vA[acol] = 1.f;                      // A starts as identity

  int cnt = NTOT - c * CHUNK;
  cnt = cnt < 0 ? 0 : (cnt > CHUNK ? CHUNK : cnt);

  auto stage = [&](int gg, float* lb) {          // 10 loads
    int b[4];
#pragma unroll
    for (int cc = 0; cc < 4; ++cc) b[cc] = iminc((cb + cc) * CHUNK + gg * G, CLAMPI);
    GLOAD_LDS16(a + (size_t)b[0] * 64u + lane * 4, lb);
    GLOAD_LDS16(a + (size_t)b[1] * 64u + lane * 4, lb + 260);
    GLOAD_LDS16(a + (size_t)b[2] * 64u + lane * 4, lb + 520);
    GLOAD_LDS16(a + (size_t)b[3] * 64u + lane * 4, lb + 780);
    GLOAD_LDS4(q + (size_t)(lane < 32 ? b[0] : b[1]) * 8u + (lane & 31), lb + K1_BQ);
    GLOAD_LDS4(q + (size_t)(lane < 32 ? b[2] : b[3]) * 8u + (lane & 31), lb + K1_BQ + 68);
    GLOAD_LDS4(x + (size_t)b[0] * 16u + lane, lb + K1_BX);
    GLOAD_LDS4(x + (size_t)b[1] * 16u + lane, lb + K1_BX + 80);
    GLOAD_LDS4(x + (size_t)b[2] * 16u + lane, lb + K1_BX + 160);
    GLOAD_LDS4(x + (size_t)b[3] * 16u + lane, lb + K1_BX + 240);
  };

  stage(0, b0);
  stage(1, b1);
#pragma unroll 1
  for (int gg = 0; gg < NGPC; ++gg) {
    float* lb = b0;
    if (gg + 2 < NGPC) {
      stage(gg + 2, b2);
      WAIT_VM(20);                 // 2 stages (20 loads) stay in flight
    } else if (gg + 1 < NGPC) {
      WAIT_VM(10);
    } else {
      WAIT_VM(0);
    }
    const float* ablk = lb + g * 260;
    const float* qblk = lb + K1_BQ + (g >> 1) * 68 + (g & 1) * 32;
    const float* xblk = lb + K1_BX + g * 80;
#pragma unroll 1
    for (int e = 0; e < G; ++e) {
      const int eg = gg * G + e;
      if (eg < cnt) {
        const float* ae = ablk + e * 64;             // row-major a[m][t]
        const float xk  = xblk[e * 16 + ll];
        const float* qe = qblk + e * 8;
        float qv[8];
        *(float4*)&qv[0] = *(const float4*)(qe);
        *(float4*)&qv[4] = *(const float4*)(qe + 4);
        float nB[8], nA[8];
#pragma unroll
        for (int m = 0; m < 8; ++m) {
          float4 r0 = *(const float4*)(ae + m * 8);
          float4 r1 = *(const float4*)(ae + m * 8 + 4);
          float sB = qv[m] * xk;
          sB += r0.x * vB[0] + r0.y * vB[1] + r0.z * vB[2] + r0.w * vB[3]
              + r1.x * vB[4] + r1.y * vB[5] + r1.z * vB[6] + r1.w * vB[7];
          nB[m] = sB;
          float sA = r0.x * vA[0] + r0.y * vA[1] + r0.z * vA[2] + r0.w * vA[3]
                   + r1.x * vA[4] + r1.y * vA[5] + r1.z * vA[6] + r1.w * vA[7];
          nA[m] = sA;
        }
#pragma unroll
        for (int m = 0; m < 8; ++m) { vB[m] = nB[m]; vA[m] = nA[m]; }
      }
    }
    float* t = b0; b0 = b1; b1 = b2; b2 = t;    // rotate buffers
  }

  {
    float* dst = ws + OFF_AGGB + (size_t)c * 128u + (size_t)ll * 8u;
#pragma unroll
    for (int m = 0; m < 8; ++m) dst[m] = vB[m];
  }
  if (hasA) {
    float* dst = ws + OFF_AGGA + (size_t)c * 64u + (size_t)acol * 8u;
#pragma unroll
    for (int m = 0; m < 8; ++m) dst[m] = vA[m];
  }
}

// ---------- Phase 2a: serial scan inside each group of 64 chunks -----------
// A-tiles staged to LDS up front; B operands software-prefetched one combine
// ahead. IN-PLACE: slot <- group-local exclusive prefix.
__global__ __launch_bounds__(64) void k2a_groupscan(float* __restrict__ ws)
{
  __shared__ float sA[GRPSZ * 64];   // 16 KiB
  const int g    = blockIdx.x;
  const int lane = (int)(threadIdx.x & 63);
  const bool isB = lane < 16;
  const bool isA = (lane >= 16) && (lane < 24);
  const int bcol = lane & 15;
  const int acol = (lane - 16) & 7;

#pragma unroll 1
  for (int t = 0; t < 16; ++t)
    GLOAD_LDS16(ws + OFF_AGGA + (size_t)g * (GRPSZ * 64u) + t * 256 + lane * 4,
                sA + t * 256);

  float v[8];
#pragma unroll
  for (int m = 0; m < 8; ++m) v[m] = 0.f;
  if (isA) v[acol] = 1.f;

  float4 nb0, nb1;
  {
    const float* s = ws + OFF_AGGB + (size_t)(g * GRPSZ) * 128u + (size_t)bcol * 8u;
    nb0 = *(const float4*)s; nb1 = *(const float4*)(s + 4);
  }
  WAIT_VM(0);   // LDS staging complete

#pragma unroll 1
  for (int j = 0; j < GRPSZ; ++j) {
    const int c = g * GRPSZ + j;
    float bB[8] = {nb0.x, nb0.y, nb0.z, nb0.w, nb1.x, nb1.y, nb1.z, nb1.w};
    if (j + 1 < GRPSZ) {
      const float* s = ws + OFF_AGGB + (size_t)(c + 1) * 128u + (size_t)bcol * 8u;
      nb0 = *(const float4*)s; nb1 = *(const float4*)(s + 4);
    }
    if (isB) {
      float* dst = ws + OFF_AGGB + (size_t)c * 128u + (size_t)bcol * 8u;
#pragma unroll
      for (int m = 0; m < 8; ++m) dst[m] = v[m];
    } else if (isA) {
      float* dst = ws + OFF_AGGA + (size_t)c * 64u + (size_t)acol * 8u;
#pragma unroll
      for (int m = 0; m < 8; ++m) dst[m] = v[m];
    }
    const float* Aj = sA + j * 64;
    float nv[8];
#pragma unroll
    for (int m = 0; m < 8; ++m) nv[m] = 0.f;
#pragma unroll
    for (int t = 0; t < 8; ++t) {
      float4 col0 = *(const float4*)(Aj + t * 8);
      float4 col1 = *(const float4*)(Aj + t * 8 + 4);
      nv[0] += col0.x * v[t]; nv[1] += col0.y * v[t];
      nv[2] += col0.z * v[t]; nv[3] += col0.w * v[t];
      nv[4] += col1.x * v[t]; nv[5] += col1.y * v[t];
      nv[6] += col1.z * v[t]; nv[7] += col1.w * v[t];
    }
    if (isB) {
#pragma unroll
      for (int m = 0; m < 8; ++m) nv[m] += bB[m];
    }
#pragma unroll
    for (int m = 0; m < 8; ++m) v[m] = nv[m];
  }

  if (isB) {
    float* dst = ws + OFF_GAGB + (size_t)g * 128u + (size_t)bcol * 8u;
#pragma unroll
    for (int m = 0; m < 8; ++m) dst[m] = v[m];
  } else if (isA) {
    float* dst = ws + OFF_GAGA + (size_t)g * 64u + (size_t)acol * 8u;
#pragma unroll
    for (int m = 0; m < 8; ++m) dst[m] = v[m];
  }
}

// ---------- Phase 2b: single-wave scan over the NGRP group aggregates ------
// IN-PLACE on GAGB: slot <- group-exclusive B prefix. GAGA read-only.
__global__ __launch_bounds__(64) void k2b_topscan(float* __restrict__ ws)
{
  __shared__ float sA[NGRP * 64];    // 32 KiB
  const int lane = (int)(threadIdx.x & 63);
  const bool isB = lane < 16;
  const bool isA = (lane >= 16) && (lane < 24);
  const int bcol = lane & 15;
  const int acol = (lane - 16) & 7;

#pragma unroll 1
  for (int t = 0; t < 32; ++t)
    GLOAD_LDS16(ws + OFF_GAGA + t * 256 + lane * 4, sA + t * 256);

  float v[8];
#pragma unroll
  for (int m = 0; m < 8; ++m) v[m] = 0.f;
  if (isA) v[acol] = 1.f;

  float4 nb0, nb1;
  {
    const float* s = ws + OFF_GAGB + (size_t)bcol * 8u;
    nb0 = *(const float4*)s; nb1 = *(const float4*)(s + 4);
  }
  WAIT_VM(0);

#pragma unroll 1
  for (int j = 0; j < NGRP; ++j) {
    float bB[8] = {nb0.x, nb0.y, nb0.z, nb0.w, nb1.x, nb1.y, nb1.z, nb1.w};
    if (j + 1 < NGRP) {
      const float* s = ws + OFF_GAGB + (size_t)(j + 1) * 128u + (size_t)bcol * 8u;
      nb0 = *(const float4*)s; nb1 = *(const float4*)(s + 4);
    }
    if (isB) {
      float* dst = ws + OFF_GAGB + (size_t)j * 128u + (size_t)bcol * 8u;
#pragma unroll
      for (int m = 0; m < 8; ++m) dst[m] = v[m];
    }
    const float* Aj = sA + j * 64;
    float nv[8];
#pragma unroll
    for (int m = 0; m < 8; ++m) nv[m] = 0.f;
#pragma unroll
    for (int t = 0; t < 8; ++t) {
      float4 col0 = *(const float4*)(Aj + t * 8);
      float4 col1 = *(const float4*)(Aj + t * 8 + 4);
      nv[0] += col0.x * v[t]; nv[1] += col0.y * v[t];
      nv[2] += col0.z * v[t]; nv[3] += col0.w * v[t];
      nv[4] += col1.x * v[t]; nv[5] += col1.y * v[t];
      nv[6] += col1.z * v[t]; nv[7] += col1.w * v[t];
    }
    if (isB) {
#pragma unroll
      for (int m = 0; m < 8; ++m) nv[m] += bB[m];
    }
#pragma unroll
    for (int m = 0; m < 8; ++m) v[m] = nv[m];
  }
}

// ---------- Phase 3: replay each chunk from its carry, emit y --------------
// 4 chunks/wave: group g = lane>>4 owns chunk wave*4+g; k = lane&15 is the
// f-column. All 64 lanes compute and store.
// Buffer: A g*260 | q pairs 1040/1108 | p pairs 1176/1244 | x 1312+g*80.
#define K3_BQ 1040
#define K3_BP 1176
#define K3_BX 1312
#define K3_BUF 1616
__global__ __launch_bounds__(256, 2) void k3_output(
    const float* __restrict__ p, const float* __restrict__ q,
    const float* __restrict__ a, const float* __restrict__ x,
    const float* __restrict__ ws, float* __restrict__ out)
{
  __shared__ float sm3[4 * 3 * K3_BUF];   // 77568 B
  const int wv   = (int)(threadIdx.x >> 6);
  const int wave = blockIdx.x * 4 + wv;          // 0..2047
  const int lane = (int)(threadIdx.x & 63);
  const int g    = lane >> 4;                    // chunk 0..3 of the quad
  const int k    = lane & 15;                    // f column
  const int c    = wave * 4 + g;
  const int grp  = c >> 6;                       // GRPSZ = 64

  const int cb = wave * 4;
  float* b0 = sm3 + wv * (3 * K3_BUF);
  float* b1 = b0 + K3_BUF;
  float* b2 = b0 + 2 * K3_BUF;

  auto stage = [&](int gg, float* lb) {          // 12 loads
    int b[4];
#pragma unroll
    for (int cc = 0; cc < 4; ++cc) b[cc] = iminc((cb + cc) * CHUNK + gg * G, CLAMPI);
    GLOAD_LDS16(a + (size_t)b[0] * 64u + lane * 4, lb);
    GLOAD_LDS16(a + (size_t)b[1] * 64u + lane * 4, lb + 260);
    GLOAD_LDS16(a + (size_t)b[2] * 64u + lane * 4, lb + 520);
    GLOAD_LDS16(a + (size_t)b[3] * 64u + lane * 4, lb + 780);
    GLOAD_LDS4(q + (size_t)(lane < 32 ? b[0] : b[1]) * 8u + (lane & 31), lb + K3_BQ);
    GLOAD_LDS4(q + (size_t)(lane < 32 ? b[2] : b[3]) * 8u + (lane & 31), lb + K3_BQ + 68);
    GLOAD_LDS4(p + (size_t)(lane < 32 ? b[0] : b[1]) * 8u + (lane & 31), lb + K3_BP);
    GLOAD_LDS4(p + (size_t)(lane < 32 ? b[2] : b[3]) * 8u + (lane & 31), lb + K3_BP + 68);
    GLOAD_LDS4(x + (size_t)b[0] * 16u + lane, lb + K3_BX);
    GLOAD_LDS4(x + (size_t)b[1] * 16u + lane, lb + K3_BX + 80);
    GLOAD_LDS4(x + (size_t)b[2] * 16u + lane, lb + K3_BX + 160);
    GLOAD_LDS4(x + (size_t)b[3] * 16u + lane, lb + K3_BX + 240);
  };

  stage(0, b0);   // issue first, hide under the f-init below
  stage(1, b1);

  // init f column k = prefA_c @ grpB[:,k] + prefB_c[:,k]  (ws is col-major,
  // streamed column-by-column to stay register-lean)
  const float* __restrict__ pA  = ws + OFF_AGGA + (size_t)c * 64u;
  const float* __restrict__ gBp = ws + OFF_GAGB + (size_t)grp * 128u + (size_t)k * 8u;
  const float* __restrict__ lBp = ws + OFF_AGGB + (size_t)c * 128u + (size_t)k * 8u;
  float gcol[8];
#pragma unroll
  for (int t = 0; t < 8; ++t) gcol[t] = gBp[t];
  float f[8];
#pragma unroll
  for (int m = 0; m < 8; ++m) f[m] = lBp[m];
#pragma unroll
  for (int t = 0; t < 8; ++t) {
    float4 col0 = *(const float4*)(pA + t * 8);
    float4 col1 = *(const float4*)(pA + t * 8 + 4);
    const float gt = gcol[t];
    f[0] += col0.x * gt; f[1] += col0.y * gt;
    f[2] += col0.z * gt; f[3] += col0.w * gt;
    f[4] += col1.x * gt; f[5] += col1.y * gt;
    f[6] += col1.z * gt; f[7] += col1.w * gt;
  }

  int cnt = NTOT - c * CHUNK;
  cnt = cnt < 0 ? 0 : (cnt > CHUNK ? CHUNK : cnt);

#pragma unroll 1
  for (int gg = 0; gg < NGPC; ++gg) {
    float* lb = b0;
    if (gg + 2 < NGPC) {
      stage(gg + 2, b2);
      WAIT_VM(24);                 // 2 stages (24 loads) stay in flight
    } else if (gg + 1 < NGPC) {
      WAIT_VM(12);
    } else {
      WAIT_VM(0);
    }
    const float* ablk = lb + g * 260;
    const float* qblk = lb + K3_BQ + (g >> 1) * 68 + (g & 1) * 32;
    const float* pblk = lb + K3_BP + (g >> 1) * 68 + (g & 1) * 32;
    const float* xblk = lb + K3_BX + g * 80;
#pragma unroll 1
    for (int e = 0; e < G; ++e) {
      const int eg = gg * G + e;
      if (eg < cnt) {
        const int i = c * CHUNK + eg;
        const float* ae = ablk + e * 64;             // row-major a
        const float* qe = qblk + e * 8;
        const float* pe = pblk + e * 8;
        const float xk  = xblk[e * 16 + k];
        float qv[8], pv[8];
        *(float4*)&qv[0] = *(const float4*)(qe);
        *(float4*)&qv[4] = *(const float4*)(qe + 4);
        *(float4*)&pv[0] = *(const float4*)(pe);
        *(float4*)&pv[4] = *(const float4*)(pe + 4);

        float y = 0.f;
#pragma unroll
        for (int m = 0; m < 8; ++m) y += pv[m] * f[m];
        out[(size_t)i * 16u + k] = y;

        float nf[8];
#pragma unroll
        for (int m = 0; m < 8; ++m) {
          float4 r0 = *(const float4*)(ae + m * 8);
          float4 r1 = *(const float4*)(ae + m * 8 + 4);
          float s = qv[m] * xk;
          s += r0.x * f[0] + r0.y * f[1] + r0.z * f[2] + r0.w * f[3]
             + r1.x * f[4] + r1.y * f[5] + r1.z * f[6] + r1.w * f[7];
          nf[m] = s;
        }
#pragma unroll
        for (int m = 0; m < 8; ++m) f[m] = nf[m];
      }
    }
    float* t = b0; b0 = b1; b1 = b2; b2 = t;    // rotate buffers
  }
}

extern "C" void kernel_launch(void* const* d_in, const int* in_sizes, int n_in,
                              void* d_out, int out_size, void* d_ws, size_t ws_size,
                              hipStream_t stream)
{
  const float* p = (const float*)d_in[0];
  const float* q = (const float*)d_in[1];
  const float* a = (const float*)d_in[2];
  const float* x = (const float*)d_in[3];
  float* out = (float*)d_out;
  float* ws  = (float*)d_ws;

  hipLaunchKernelGGL(k1_aggregate, dim3(NCHUNK / 4 / 4), dim3(256), 0, stream, q, a, x, ws);
  hipLaunchKernelGGL(k2a_groupscan, dim3(NGRP), dim3(64), 0, stream, ws);
  hipLaunchKernelGGL(k2b_topscan, dim3(1), dim3(64), 0, stream, ws);
  hipLaunchKernelGGL(k3_output, dim3(NCHUNK / 4 / 4), dim3(256), 0, stream, p, q, a, x, ws, out);
}

// Round 7
// 187.223 us; speedup vs baseline: 1.1509x; 1.0548x over previous
//
#include <hip/hip_runtime.h>

// StrictLowerTriQSM: f_{i+1} = a_i @ f_i + outer(q_i, x_i), y_i = p_i @ f_i
// N=500000, M=8, K=16. Blocked associative scan, 4 kernels.
// Round 7: r6 structure (4 chunks/wave, staggered LDS multicast, triple
// buffer) + manual 2-stage REGISTER pipeline over elements (A_0/A_1 frags),
// ping-pong state arrays (no copy-back movs), guard-free k1 inner loop
// (junk tail flows only into unused outputs), store-only guard in k3.

#define NTOT 500000
#define CHUNK 64
#define NCHUNK 8192            // 8192*64 = 524288 >= 500000
#define G 4                    // elements per staging group
#define NGPC 16                // groups per chunk
#define GRPSZ 64
#define NGRP 128               // 8192/64
#define CLAMPI 499996          // NTOT - G

// workspace float offsets (COLUMN-major tiles: [c][col][row])
#define OFF_AGGA  0u           // NCHUNK*64  = 524288
#define OFF_AGGB  524288u      // NCHUNK*128 = 1048576
#define OFF_GAGA  1572864u     // NGRP*64    = 8192
#define OFF_GAGB  1581056u     // NGRP*128   = 16384

#define AS1(p) ((const __attribute__((address_space(1))) void*)(p))
#define AS3(p) ((__attribute__((address_space(3))) void*)(p))
#define GLOAD_LDS16(gp, lp) __builtin_amdgcn_global_load_lds(AS1(gp), AS3(lp), 16, 0, 0)
#define GLOAD_LDS4(gp, lp)  __builtin_amdgcn_global_load_lds(AS1(gp), AS3(lp), 4, 0, 0)
#define WAIT_VM(n) asm volatile("s_waitcnt vmcnt(" #n ")" ::: "memory")

static __device__ __forceinline__ int iminc(int a, int b) { return a < b ? a : b; }

#define LOADFRAG(FR, EIDX) do {                                              \
    const float* aep_ = ablk + (EIDX) * 64;                                  \
    _Pragma("unroll") for (int mm = 0; mm < 8; ++mm) {                       \
      FR[2*mm]   = *(const float4*)(aep_ + mm * 8);                          \
      FR[2*mm+1] = *(const float4*)(aep_ + mm * 8 + 4);                      \
    }                                                                        \
  } while (0)

// ---------------- Phase 1: per-chunk aggregates (A_blk, B_blk) -------------
// 4 chunks/wave: group g = lane>>4 owns chunk wave*4+g; ll = lane&15.
// Lane ll: B-column ll; lanes ll in [8,16) also carry A-column (ll-8).
// Buffer (floats): A g*260 (16B stagger) | q 1040 + (g>>1)*68 + (g&1)*32
// | x 1176 + g*80. BUF = 1480. Triple-buffered.
#define K1_BQ 1040
#define K1_BX 1176
#define K1_BUF 1480

#define K1_COMP(FR, EIDX, VBS, VAS, VBD, VAD) do {                           \
    const float xk_ = xblk[(EIDX) * 16 + ll];                                \
    const float4 q0_ = *(const float4*)(qblk + (EIDX) * 8);                  \
    const float4 q1_ = *(const float4*)(qblk + (EIDX) * 8 + 4);              \
    const float qv_[8] = {q0_.x,q0_.y,q0_.z,q0_.w,q1_.x,q1_.y,q1_.z,q1_.w};  \
    _Pragma("unroll") for (int mm = 0; mm < 8; ++mm) {                       \
      const float4 r0_ = FR[2*mm], r1_ = FR[2*mm+1];                         \
      VBD[mm] = qv_[mm] * xk_                                                \
              + r0_.x*VBS[0] + r0_.y*VBS[1] + r0_.z*VBS[2] + r0_.w*VBS[3]    \
              + r1_.x*VBS[4] + r1_.y*VBS[5] + r1_.z*VBS[6] + r1_.w*VBS[7];   \
      VAD[mm] = r0_.x*VAS[0] + r0_.y*VAS[1] + r0_.z*VAS[2] + r0_.w*VAS[3]    \
              + r1_.x*VAS[4] + r1_.y*VAS[5] + r1_.z*VAS[6] + r1_.w*VAS[7];   \
    }                                                                        \
  } while (0)

__global__ __launch_bounds__(256, 2) void k1_aggregate(
    const float* __restrict__ q, const float* __restrict__ a,
    const float* __restrict__ x, float* __restrict__ ws)
{
  __shared__ float sm[4 * 3 * K1_BUF];   // 71040 B
  const int wv   = (int)(threadIdx.x >> 6);
  const int wave = blockIdx.x * 4 + wv;          // 0..2047
  const int lane = (int)(threadIdx.x & 63);
  const int g    = lane >> 4;                    // chunk 0..3 of the quad
  const int ll   = lane & 15;
  const int c    = wave * 4 + g;                 // this lane's chunk
  const bool hasA = ll >= 8;
  const int acol = ll & 7;

  const int cb = wave * 4;
  float* b0 = sm + wv * (3 * K1_BUF);
  float* b1 = b0 + K1_BUF;
  float* b2 = b0 + 2 * K1_BUF;

  float vB0[8], vA0[8], vB1[8], vA1[8];
#pragma unroll
  for (int m = 0; m < 8; ++m) { vB0[m] = 0.f; vA0[m] = 0.f; }
  if (hasA) vA0[acol] = 1.f;                     // A starts as identity

  auto stage = [&](int gg, float* lb) {          // 10 loads
    int b[4];
#pragma unroll
    for (int cc = 0; cc < 4; ++cc) b[cc] = iminc((cb + cc) * CHUNK + gg * G, CLAMPI);
    GLOAD_LDS16(a + (size_t)b[0] * 64u + lane * 4, lb);
    GLOAD_LDS16(a + (size_t)b[1] * 64u + lane * 4, lb + 260);
    GLOAD_LDS16(a + (size_t)b[2] * 64u + lane * 4, lb + 520);
    GLOAD_LDS16(a + (size_t)b[3] * 64u + lane * 4, lb + 780);
    GLOAD_LDS4(q + (size_t)(lane < 32 ? b[0] : b[1]) * 8u + (lane & 31), lb + K1_BQ);
    GLOAD_LDS4(q + (size_t)(lane < 32 ? b[2] : b[3]) * 8u + (lane & 31), lb + K1_BQ + 68);
    GLOAD_LDS4(x + (size_t)b[0] * 16u + lane, lb + K1_BX);
    GLOAD_LDS4(x + (size_t)b[1] * 16u + lane, lb + K1_BX + 80);
    GLOAD_LDS4(x + (size_t)b[2] * 16u + lane, lb + K1_BX + 160);
    GLOAD_LDS4(x + (size_t)b[3] * 16u + lane, lb + K1_BX + 240);
  };

  stage(0, b0);
  stage(1, b1);
#pragma unroll 1
  for (int gg = 0; gg < NGPC; ++gg) {
    float* lb = b0;
    if (gg + 2 < NGPC) {
      stage(gg + 2, b2);
      WAIT_VM(20);                 // 2 stages (20 loads) stay in flight
    } else if (gg + 1 < NGPC) {
      WAIT_VM(10);
    } else {
      WAIT_VM(0);
    }
    const float* ablk = lb + g * 260;
    const float* qblk = lb + K1_BQ + (g >> 1) * 68 + (g & 1) * 32;
    const float* xblk = lb + K1_BX + g * 80;

    float4 A_0[16], A_1[16];
    LOADFRAG(A_0, 0);
    LOADFRAG(A_1, 1);  K1_COMP(A_0, 0, vB0, vA0, vB1, vA1);
    LOADFRAG(A_0, 2);  K1_COMP(A_1, 1, vB1, vA1, vB0, vA0);
    LOADFRAG(A_1, 3);  K1_COMP(A_0, 2, vB0, vA0, vB1, vA1);
                       K1_COMP(A_1, 3, vB1, vA1, vB0, vA0);

    float* t = b0; b0 = b1; b1 = b2; b2 = t;    // rotate buffers
  }

  {
    float* dst = ws + OFF_AGGB + (size_t)c * 128u + (size_t)ll * 8u;
#pragma unroll
    for (int m = 0; m < 8; ++m) dst[m] = vB0[m];
  }
  if (hasA) {
    float* dst = ws + OFF_AGGA + (size_t)c * 64u + (size_t)acol * 8u;
#pragma unroll
    for (int m = 0; m < 8; ++m) dst[m] = vA0[m];
  }
}

// ---------- Phase 2a: serial scan inside each group of 64 chunks -----------
__global__ __launch_bounds__(64) void k2a_groupscan(float* __restrict__ ws)
{
  __shared__ float sA[GRPSZ * 64];   // 16 KiB
  const int g    = blockIdx.x;
  const int lane = (int)(threadIdx.x & 63);
  const bool isB = lane < 16;
  const bool isA = (lane >= 16) && (lane < 24);
  const int bcol = lane & 15;
  const int acol = (lane - 16) & 7;

#pragma unroll 1
  for (int t = 0; t < 16; ++t)
    GLOAD_LDS16(ws + OFF_AGGA + (size_t)g * (GRPSZ * 64u) + t * 256 + lane * 4,
                sA + t * 256);

  float v[8];
#pragma unroll
  for (int m = 0; m < 8; ++m) v[m] = 0.f;
  if (isA) v[acol] = 1.f;

  float4 nb0, nb1;
  {
    const float* s = ws + OFF_AGGB + (size_t)(g * GRPSZ) * 128u + (size_t)bcol * 8u;
    nb0 = *(const float4*)s; nb1 = *(const float4*)(s + 4);
  }
  WAIT_VM(0);   // LDS staging complete

#pragma unroll 1
  for (int j = 0; j < GRPSZ; ++j) {
    const int c = g * GRPSZ + j;
    float bB[8] = {nb0.x, nb0.y, nb0.z, nb0.w, nb1.x, nb1.y, nb1.z, nb1.w};
    if (j + 1 < GRPSZ) {
      const float* s = ws + OFF_AGGB + (size_t)(c + 1) * 128u + (size_t)bcol * 8u;
      nb0 = *(const float4*)s; nb1 = *(const float4*)(s + 4);
    }
    if (isB) {
      float* dst = ws + OFF_AGGB + (size_t)c * 128u + (size_t)bcol * 8u;
#pragma unroll
      for (int m = 0; m < 8; ++m) dst[m] = v[m];
    } else if (isA) {
      float* dst = ws + OFF_AGGA + (size_t)c * 64u + (size_t)acol * 8u;
#pragma unroll
      for (int m = 0; m < 8; ++m) dst[m] = v[m];
    }
    const float* Aj = sA + j * 64;
    float nv[8];
#pragma unroll
    for (int m = 0; m < 8; ++m) nv[m] = 0.f;
#pragma unroll
    for (int t = 0; t < 8; ++t) {
      float4 col0 = *(const float4*)(Aj + t * 8);
      float4 col1 = *(const float4*)(Aj + t * 8 + 4);
      nv[0] += col0.x * v[t]; nv[1] += col0.y * v[t];
      nv[2] += col0.z * v[t]; nv[3] += col0.w * v[t];
      nv[4] += col1.x * v[t]; nv[5] += col1.y * v[t];
      nv[6] += col1.z * v[t]; nv[7] += col1.w * v[t];
    }
    if (isB) {
#pragma unroll
      for (int m = 0; m < 8; ++m) nv[m] += bB[m];
    }
#pragma unroll
    for (int m = 0; m < 8; ++m) v[m] = nv[m];
  }

  if (isB) {
    float* dst = ws + OFF_GAGB + (size_t)g * 128u + (size_t)bcol * 8u;
#pragma unroll
    for (int m = 0; m < 8; ++m) dst[m] = v[m];
  } else if (isA) {
    float* dst = ws + OFF_GAGA + (size_t)g * 64u + (size_t)acol * 8u;
#pragma unroll
    for (int m = 0; m < 8; ++m) dst[m] = v[m];
  }
}

// ---------- Phase 2b: single-wave scan over the NGRP group aggregates ------
__global__ __launch_bounds__(64) void k2b_topscan(float* __restrict__ ws)
{
  __shared__ float sA[NGRP * 64];    // 32 KiB
  const int lane = (int)(threadIdx.x & 63);
  const bool isB = lane < 16;
  const bool isA = (lane >= 16) && (lane < 24);
  const int bcol = lane & 15;
  const int acol = (lane - 16) & 7;

#pragma unroll 1
  for (int t = 0; t < 32; ++t)
    GLOAD_LDS16(ws + OFF_GAGA + t * 256 + lane * 4, sA + t * 256);

  float v[8];
#pragma unroll
  for (int m = 0; m < 8; ++m) v[m] = 0.f;
  if (isA) v[acol] = 1.f;

  float4 nb0, nb1;
  {
    const float* s = ws + OFF_GAGB + (size_t)bcol * 8u;
    nb0 = *(const float4*)s; nb1 = *(const float4*)(s + 4);
  }
  WAIT_VM(0);

#pragma unroll 1
  for (int j = 0; j < NGRP; ++j) {
    float bB[8] = {nb0.x, nb0.y, nb0.z, nb0.w, nb1.x, nb1.y, nb1.z, nb1.w};
    if (j + 1 < NGRP) {
      const float* s = ws + OFF_GAGB + (size_t)(j + 1) * 128u + (size_t)bcol * 8u;
      nb0 = *(const float4*)s; nb1 = *(const float4*)(s + 4);
    }
    if (isB) {
      float* dst = ws + OFF_GAGB + (size_t)j * 128u + (size_t)bcol * 8u;
#pragma unroll
      for (int m = 0; m < 8; ++m) dst[m] = v[m];
    }
    const float* Aj = sA + j * 64;
    float nv[8];
#pragma unroll
    for (int m = 0; m < 8; ++m) nv[m] = 0.f;
#pragma unroll
    for (int t = 0; t < 8; ++t) {
      float4 col0 = *(const float4*)(Aj + t * 8);
      float4 col1 = *(const float4*)(Aj + t * 8 + 4);
      nv[0] += col0.x * v[t]; nv[1] += col0.y * v[t];
      nv[2] += col0.z * v[t]; nv[3] += col0.w * v[t];
      nv[4] += col1.x * v[t]; nv[5] += col1.y * v[t];
      nv[6] += col1.z * v[t]; nv[7] += col1.w * v[t];
    }
    if (isB) {
#pragma unroll
      for (int m = 0; m < 8; ++m) nv[m] += bB[m];
    }
#pragma unroll
    for (int m = 0; m < 8; ++m) v[m] = nv[m];
  }
}

// ---------- Phase 3: replay each chunk from its carry, emit y --------------
// 4 chunks/wave: g = lane>>4 owns chunk wave*4+g; k = lane&15 is the
// f-column. All 64 lanes compute and store. Register-pipelined like k1.
#define K3_BQ 1040
#define K3_BP 1176
#define K3_BX 1312
#define K3_BUF 1616

#define K3_COMP(FR, EIDX, FS, FD) do {                                       \
    const float xk_ = xblk[(EIDX) * 16 + k];                                 \
    const float4 q0_ = *(const float4*)(qblk + (EIDX) * 8);                  \
    const float4 q1_ = *(const float4*)(qblk + (EIDX) * 8 + 4);              \
    const float4 p0_ = *(const float4*)(pblk + (EIDX) * 8);                  \
    const float4 p1_ = *(const float4*)(pblk + (EIDX) * 8 + 4);              \
    const float y_ = p0_.x*FS[0] + p0_.y*FS[1] + p0_.z*FS[2] + p0_.w*FS[3]   \
                   + p1_.x*FS[4] + p1_.y*FS[5] + p1_.z*FS[6] + p1_.w*FS[7];  \
    const int i_ = c * CHUNK + gg * G + (EIDX);                              \
    if (i_ < NTOT) out[(size_t)i_ * 16u + k] = y_;                           \
    const float qv_[8] = {q0_.x,q0_.y,q0_.z,q0_.w,q1_.x,q1_.y,q1_.z,q1_.w};  \
    _Pragma("unroll") for (int mm = 0; mm < 8; ++mm) {                       \
      const float4 r0_ = FR[2*mm], r1_ = FR[2*mm+1];                         \
      FD[mm] = qv_[mm] * xk_                                                 \
             + r0_.x*FS[0] + r0_.y*FS[1] + r0_.z*FS[2] + r0_.w*FS[3]         \
             + r1_.x*FS[4] + r1_.y*FS[5] + r1_.z*FS[6] + r1_.w*FS[7];        \
    }                                                                        \
  } while (0)

__global__ __launch_bounds__(256, 2) void k3_output(
    const float* __restrict__ p, const float* __restrict__ q,
    const float* __restrict__ a, const float* __restrict__ x,
    const float* __restrict__ ws, float* __restrict__ out)
{
  __shared__ float sm3[4 * 3 * K3_BUF];   // 77568 B
  const int wv   = (int)(threadIdx.x >> 6);
  const int wave = blockIdx.x * 4 + wv;          // 0..2047
  const int lane = (int)(threadIdx.x & 63);
  const int g    = lane >> 4;                    // chunk 0..3 of the quad
  const int k    = lane & 15;                    // f column
  const int c    = wave * 4 + g;
  const int grp  = c >> 6;                       // GRPSZ = 64

  const int cb = wave * 4;
  float* b0 = sm3 + wv * (3 * K3_BUF);
  float* b1 = b0 + K3_BUF;
  float* b2 = b0 + 2 * K3_BUF;

  auto stage = [&](int gg, float* lb) {          // 12 loads
    int b[4];
#pragma unroll
    for (int cc = 0; cc < 4; ++cc) b[cc] = iminc((cb + cc) * CHUNK + gg * G, CLAMPI);
    GLOAD_LDS16(a + (size_t)b[0] * 64u + lane * 4, lb);
    GLOAD_LDS16(a + (size_t)b[1] * 64u + lane * 4, lb + 260);
    GLOAD_LDS16(a + (size_t)b[2] * 64u + lane * 4, lb + 520);
    GLOAD_LDS16(a + (size_t)b[3] * 64u + lane * 4, lb + 780);
    GLOAD_LDS4(q + (size_t)(lane < 32 ? b[0] : b[1]) * 8u + (lane & 31), lb + K3_BQ);
    GLOAD_LDS4(q + (size_t)(lane < 32 ? b[2] : b[3]) * 8u + (lane & 31), lb + K3_BQ + 68);
    GLOAD_LDS4(p + (size_t)(lane < 32 ? b[0] : b[1]) * 8u + (lane & 31), lb + K3_BP);
    GLOAD_LDS4(p + (size_t)(lane < 32 ? b[2] : b[3]) * 8u + (lane & 31), lb + K3_BP + 68);
    GLOAD_LDS4(x + (size_t)b[0] * 16u + lane, lb + K3_BX);
    GLOAD_LDS4(x + (size_t)b[1] * 16u + lane, lb + K3_BX + 80);
    GLOAD_LDS4(x + (size_t)b[2] * 16u + lane, lb + K3_BX + 160);
    GLOAD_LDS4(x + (size_t)b[3] * 16u + lane, lb + K3_BX + 240);
  };

  stage(0, b0);   // issue first, hide under the f-init below
  stage(1, b1);

  // init f column k = prefA_c @ grpB[:,k] + prefB_c[:,k]  (ws is col-major)
  const float* __restrict__ pA  = ws + OFF_AGGA + (size_t)c * 64u;
  const float* __restrict__ gBp = ws + OFF_GAGB + (size_t)grp * 128u + (size_t)k * 8u;
  const float* __restrict__ lBp = ws + OFF_AGGB + (size_t)c * 128u + (size_t)k * 8u;
  float gcol[8];
#pragma unroll
  for (int t = 0; t < 8; ++t) gcol[t] = gBp[t];
  float f0[8], f1[8];
#pragma unroll
  for (int m = 0; m < 8; ++m) f0[m] = lBp[m];
#pragma unroll
  for (int t = 0; t < 8; ++t) {
    float4 col0 = *(const float4*)(pA + t * 8);
    float4 col1 = *(const float4*)(pA + t * 8 + 4);
    const float gt = gcol[t];
    f0[0] += col0.x * gt; f0[1] += col0.y * gt;
    f0[2] += col0.z * gt; f0[3] += col0.w * gt;
    f0[4] += col1.x * gt; f0[5] += col1.y * gt;
    f0[6] += col1.z * gt; f0[7] += col1.w * gt;
  }

#pragma unroll 1
  for (int gg = 0; gg < NGPC; ++gg) {
    float* lb = b0;
    if (gg + 2 < NGPC) {
      stage(gg + 2, b2);
      WAIT_VM(24);                 // 2 stages (24 loads) stay in flight
    } else if (gg + 1 < NGPC) {
      WAIT_VM(12);
    } else {
      WAIT_VM(0);
    }
    const float* ablk = lb + g * 260;
    const float* qblk = lb + K3_BQ + (g >> 1) * 68 + (g & 1) * 32;
    const float* pblk = lb + K3_BP + (g >> 1) * 68 + (g & 1) * 32;
    const float* xblk = lb + K3_BX + g * 80;

    float4 A_0[16], A_1[16];
    LOADFRAG(A_0, 0);
    LOADFRAG(A_1, 1);  K3_COMP(A_0, 0, f0, f1);
    LOADFRAG(A_0, 2);  K3_COMP(A_1, 1, f1, f0);
    LOADFRAG(A_1, 3);  K3_COMP(A_0, 2, f0, f1);
                       K3_COMP(A_1, 3, f1, f0);

    float* t = b0; b0 = b1; b1 = b2; b2 = t;    // rotate buffers
  }
}

extern "C" void kernel_launch(void* const* d_in, const int* in_sizes, int n_in,
                              void* d_out, int out_size, void* d_ws, size_t ws_size,
                              hipStream_t stream)
{
  const float* p = (const float*)d_in[0];
  const float* q = (const float*)d_in[1];
  const float* a = (const float*)d_in[2];
  const float* x = (const float*)d_in[3];
  float* out = (float*)d_out;
  float* ws  = (float*)d_ws;

  hipLaunchKernelGGL(k1_aggregate, dim3(NCHUNK / 4 / 4), dim3(256), 0, stream, q, a, x, ws);
  hipLaunchKernelGGL(k2a_groupscan, dim3(NGRP), dim3(64), 0, stream, ws);
  hipLaunchKernelGGL(k2b_topscan, dim3(1), dim3(64), 0, stream, ws);
  hipLaunchKernelGGL(k3_output, dim3(NCHUNK / 4 / 4), dim3(256), 0, stream, p, q, a, x, ws, out);
}

// Round 8
// 158.642 us; speedup vs baseline: 1.3582x; 1.1802x over previous
//
#include <hip/hip_runtime.h>

// StrictLowerTriQSM: f_{i+1} = a_i @ f_i + outer(q_i, x_i), y_i = p_i @ f_i
// N=500000, M=8, K=16. Blocked associative scan.
// Round 8: NCHUNK=16384/CHUNK=32 (4 waves/SIMD at 4 chunks/wave), G=2
// triple-buffered staging (5-6 loads/stage, 8.4-9.2 KB LDS/wave -> 4
// blocks/CU), 3-level scan (chunk->group->super), ws_size-guarded fallback
// to NCHUNK=8192 (same templates).

#define NTOT 500000

#define AS1(p) ((const __attribute__((address_space(1))) void*)(p))
#define AS3(p) ((__attribute__((address_space(3))) void*)(p))
#define GLOAD_LDS16(gp, lp) __builtin_amdgcn_global_load_lds(AS1(gp), AS3(lp), 16, 0, 0)
#define GLOAD_LDS4(gp, lp)  __builtin_amdgcn_global_load_lds(AS1(gp), AS3(lp), 4, 0, 0)
#define WAIT_VM(n) asm volatile("s_waitcnt vmcnt(" #n ")" ::: "memory")

static __device__ __forceinline__ int iminc(int a, int b) { return a < b ? a : b; }

template<int NC> struct P {
  static constexpr int CH   = (NC == 16384) ? 32 : 64;   // elements per chunk
  static constexpr int NST  = CH / 2;                    // stages (G=2)
  static constexpr int NG   = NC / 64;                   // groups
  static constexpr int NS   = NG / 64;                   // supers
  static constexpr int AGGA = 0;                         // NC*64
  static constexpr int AGGB = NC * 64;                   // NC*128
  static constexpr int GAGA = NC * 192;                  // NG*64
  static constexpr int GAGB = NC * 192 + NG * 64;        // NG*128
  static constexpr int SGA  = NC * 192 + NG * 192;       // NS*64
  static constexpr int SGB  = NC * 192 + NG * 192 + NS * 64; // NS*128
  static constexpr size_t BYTES = (size_t)(NC * 192 + NG * 192 + NS * 192) * 4u;
};

// ---------------- Phase 1: per-chunk aggregates (A_blk, B_blk) -------------
// 4 chunks/wave: g = lane>>4 owns chunk wave*4+g; ll = lane&15 = B column;
// lanes ll>=8 additionally carry A column (ll-8). Per element every lane
// computes both the B and A matvecs (shared a rows).
// LDS buffer (floats): a[2 slots][4 ch][64] | q[4][2][8] @512 | x @576
// (layout (g,e,k) -> 576 + (g>>1)*64 + (g&1)*32 + e*16 + k). BUF=704, x3.
#define K1_COMP(E, VBS, VAS, VBD, VAD) do {                                  \
    const float xk_ = xgb[(E) * 16];                                         \
    const float4 q0_ = *(const float4*)(qgb + (E) * 8);                      \
    const float4 q1_ = *(const float4*)(qgb + (E) * 8 + 4);                  \
    const float qv_[8] = {q0_.x,q0_.y,q0_.z,q0_.w,q1_.x,q1_.y,q1_.z,q1_.w};  \
    _Pragma("unroll") for (int mm = 0; mm < 8; ++mm) {                       \
      const float4 r0_ = *(const float4*)(agb + (E) * 256 + mm * 8);         \
      const float4 r1_ = *(const float4*)(agb + (E) * 256 + mm * 8 + 4);     \
      VBD[mm] = qv_[mm] * xk_                                                \
              + r0_.x*VBS[0] + r0_.y*VBS[1] + r0_.z*VBS[2] + r0_.w*VBS[3]    \
              + r1_.x*VBS[4] + r1_.y*VBS[5] + r1_.z*VBS[6] + r1_.w*VBS[7];   \
      VAD[mm] = r0_.x*VAS[0] + r0_.y*VAS[1] + r0_.z*VAS[2] + r0_.w*VAS[3]    \
              + r1_.x*VAS[4] + r1_.y*VAS[5] + r1_.z*VAS[6] + r1_.w*VAS[7];   \
    }                                                                        \
  } while (0)

template<int NC>
__global__ __launch_bounds__(256, 4) void k1_aggregate(
    const float* __restrict__ q, const float* __restrict__ a,
    const float* __restrict__ x, float* __restrict__ ws)
{
  using PP = P<NC>;
  constexpr int CH = PP::CH, NST = PP::NST;
  __shared__ float sm[4 * 3 * 704];   // 33792 B
  const int wv   = (int)(threadIdx.x >> 6);
  const int wave = blockIdx.x * 4 + wv;
  const int lane = (int)(threadIdx.x & 63);
  const int g    = lane >> 4;
  const int ll   = lane & 15;
  const int c    = wave * 4 + g;
  const bool hasA = ll >= 8;
  const int acol  = ll & 7;

  const int cb = wave * 4;
  float* b0 = sm + wv * 2112;
  float* b1 = b0 + 704;
  float* b2 = b0 + 1408;

  const int goff = g * 64;
  const int qoff = 512 + g * 16;
  const int xoff = 576 + (g >> 1) * 64 + (g & 1) * 32 + ll;

  float vB0[8], vA0[8], vB1[8], vA1[8];
#pragma unroll
  for (int m = 0; m < 8; ++m) { vB0[m] = 0.f; vA0[m] = 0.f; }
  if (hasA) vA0[acol] = 1.f;

  const int gl = lane >> 4, ql = lane & 15;
  auto stage = [&](int ss, float* lb) {          // 5 loads
    const int base = cb * CH + ss * 2;
    GLOAD_LDS16(a + (size_t)iminc(base + gl * CH,     NTOT - 1) * 64u + ql * 4, lb);
    GLOAD_LDS16(a + (size_t)iminc(base + gl * CH + 1, NTOT - 1) * 64u + ql * 4, lb + 256);
    GLOAD_LDS4 (q + (size_t)iminc(base + (lane >> 4) * CH + ((lane >> 3) & 1), NTOT - 1) * 8u  + (lane & 7),  lb + 512);
    GLOAD_LDS4 (x + (size_t)iminc(base + (lane >> 5) * CH + ((lane >> 4) & 1), NTOT - 1) * 16u + (lane & 15), lb + 576);
    GLOAD_LDS4 (x + (size_t)iminc(base + (2 + (lane >> 5)) * CH + ((lane >> 4) & 1), NTOT - 1) * 16u + (lane & 15), lb + 640);
  };

  stage(0, b0);
  stage(1, b1);
#pragma unroll 1
  for (int ss = 0; ss < NST; ++ss) {
    float* lb = b0;
    if (ss + 2 < NST) {
      stage(ss + 2, b2);
      WAIT_VM(10);
    } else if (ss + 1 < NST) {
      WAIT_VM(5);
    } else {
      WAIT_VM(0);
    }
    const float* agb = lb + goff;
    const float* qgb = lb + qoff;
    const float* xgb = lb + xoff;
    K1_COMP(0, vB0, vA0, vB1, vA1);
    K1_COMP(1, vB1, vA1, vB0, vA0);
    float* t = b0; b0 = b1; b1 = b2; b2 = t;
  }

  {
    float* dst = ws + PP::AGGB + (size_t)c * 128u + (size_t)ll * 8u;
#pragma unroll
    for (int m = 0; m < 8; ++m) dst[m] = vB0[m];
  }
  if (hasA) {
    float* dst = ws + PP::AGGA + (size_t)c * 64u + (size_t)acol * 8u;
#pragma unroll
    for (int m = 0; m < 8; ++m) dst[m] = vA0[m];
  }
}

// ---------- Phase 2 generic: serial scan of 64 items per block -------------
// LV=0: scan chunk aggregates within a group (in: AGG*, agg out: GAG*).
// LV=1: scan group aggregates within a super (in: GAG*, agg out: SG*).
// IN-PLACE: item slot <- segment-local EXCLUSIVE prefix.
template<int NC, int LV>
__global__ __launch_bounds__(64) void k2scan(float* __restrict__ ws)
{
  using PP = P<NC>;
  constexpr int OFFAIN  = (LV == 0) ? PP::AGGA : PP::GAGA;
  constexpr int OFFBIN  = (LV == 0) ? PP::AGGB : PP::GAGB;
  constexpr int OFFAOUT = (LV == 0) ? PP::GAGA : PP::SGA;
  constexpr int OFFBOUT = (LV == 0) ? PP::GAGB : PP::SGB;
  __shared__ float sA[64 * 64];   // 16 KiB
  const int g    = blockIdx.x;
  const int lane = (int)(threadIdx.x & 63);
  const bool isB = lane < 16;
  const bool isA = (lane >= 16) && (lane < 24);
  const int bcol = lane & 15;
  const int acol = (lane - 16) & 7;

#pragma unroll 1
  for (int t = 0; t < 16; ++t)
    GLOAD_LDS16(ws + OFFAIN + (size_t)g * 4096u + t * 256 + lane * 4, sA + t * 256);

  float v[8];
#pragma unroll
  for (int m = 0; m < 8; ++m) v[m] = 0.f;
  if (isA) v[acol] = 1.f;

  float4 nb0, nb1;
  {
    const float* s = ws + OFFBIN + (size_t)(g * 64) * 128u + (size_t)bcol * 8u;
    nb0 = *(const float4*)s; nb1 = *(const float4*)(s + 4);
  }
  WAIT_VM(0);

#pragma unroll 1
  for (int j = 0; j < 64; ++j) {
    const int c = g * 64 + j;
    float bB[8] = {nb0.x, nb0.y, nb0.z, nb0.w, nb1.x, nb1.y, nb1.z, nb1.w};
    if (j + 1 < 64) {
      const float* s = ws + OFFBIN + (size_t)(c + 1) * 128u + (size_t)bcol * 8u;
      nb0 = *(const float4*)s; nb1 = *(const float4*)(s + 4);
    }
    if (isB) {
      float* dst = ws + OFFBIN + (size_t)c * 128u + (size_t)bcol * 8u;
#pragma unroll
      for (int m = 0; m < 8; ++m) dst[m] = v[m];
    } else if (isA) {
      float* dst = ws + OFFAIN + (size_t)c * 64u + (size_t)acol * 8u;
#pragma unroll
      for (int m = 0; m < 8; ++m) dst[m] = v[m];
    }
    const float* Aj = sA + j * 64;
    float nv[8];
#pragma unroll
    for (int m = 0; m < 8; ++m) nv[m] = 0.f;
#pragma unroll
    for (int t = 0; t < 8; ++t) {
      float4 col0 = *(const float4*)(Aj + t * 8);
      float4 col1 = *(const float4*)(Aj + t * 8 + 4);
      nv[0] += col0.x * v[t]; nv[1] += col0.y * v[t];
      nv[2] += col0.z * v[t]; nv[3] += col0.w * v[t];
      nv[4] += col1.x * v[t]; nv[5] += col1.y * v[t];
      nv[6] += col1.z * v[t]; nv[7] += col1.w * v[t];
    }
    if (isB) {
#pragma unroll
      for (int m = 0; m < 8; ++m) nv[m] += bB[m];
    }
#pragma unroll
    for (int m = 0; m < 8; ++m) v[m] = nv[m];
  }

  if (isB) {
    float* dst = ws + OFFBOUT + (size_t)g * 128u + (size_t)bcol * 8u;
#pragma unroll
    for (int m = 0; m < 8; ++m) dst[m] = v[m];
  } else if (isA) {
    float* dst = ws + OFFAOUT + (size_t)g * 64u + (size_t)acol * 8u;
#pragma unroll
    for (int m = 0; m < 8; ++m) dst[m] = v[m];
  }
}

// ---------- Phase 2c: single-wave scan over the NS super aggregates --------
// IN-PLACE on SGB: slot <- global-exclusive B prefix. SGA read-only.
template<int NC>
__global__ __launch_bounds__(64) void k2c_topscan(float* __restrict__ ws)
{
  using PP = P<NC>;
  const int lane = (int)(threadIdx.x & 63);
  const bool isB = lane < 16;
  const int bcol = lane & 15;

  float v[8];
#pragma unroll
  for (int m = 0; m < 8; ++m) v[m] = 0.f;

#pragma unroll 1
  for (int j = 0; j < PP::NS; ++j) {
    float bB[8];
    if (isB) {
      const float* s = ws + PP::SGB + (size_t)j * 128u + (size_t)bcol * 8u;
#pragma unroll
      for (int m = 0; m < 8; ++m) bB[m] = s[m];
      float* dst = ws + PP::SGB + (size_t)j * 128u + (size_t)bcol * 8u;
#pragma unroll
      for (int m = 0; m < 8; ++m) dst[m] = v[m];
    }
    const float* Aj = ws + PP::SGA + (size_t)j * 64u;
    float nv[8];
#pragma unroll
    for (int m = 0; m < 8; ++m) nv[m] = 0.f;
#pragma unroll
    for (int t = 0; t < 8; ++t) {
      float4 col0 = *(const float4*)(Aj + t * 8);
      float4 col1 = *(const float4*)(Aj + t * 8 + 4);
      nv[0] += col0.x * v[t]; nv[1] += col0.y * v[t];
      nv[2] += col0.z * v[t]; nv[3] += col0.w * v[t];
      nv[4] += col1.x * v[t]; nv[5] += col1.y * v[t];
      nv[6] += col1.z * v[t]; nv[7] += col1.w * v[t];
    }
    if (isB) {
#pragma unroll
      for (int m = 0; m < 8; ++m) nv[m] += bB[m];
    }
#pragma unroll
    for (int m = 0; m < 8; ++m) v[m] = nv[m];
  }
}

// ---------- Phase 3: replay each chunk from its carry, emit y --------------
// 4 chunks/wave, k = lane&15 = f column; all 64 lanes compute + store.
// f-init composes 3 levels: f0 = prefB_c + prefA_c@(gB_gr + gA_gr@sB_s).
// Buffer: a[2][4][64] | q @512 | p @576 | x @640. BUF=768, x3.
#define K3_COMP(E, FS, FD) do {                                              \
    const float xk_ = xgb[(E) * 16];                                         \
    const float4 q0_ = *(const float4*)(qgb + (E) * 8);                      \
    const float4 q1_ = *(const float4*)(qgb + (E) * 8 + 4);                  \
    const float4 p0_ = *(const float4*)(pgb + (E) * 8);                      \
    const float4 p1_ = *(const float4*)(pgb + (E) * 8 + 4);                  \
    const float y_ = p0_.x*FS[0] + p0_.y*FS[1] + p0_.z*FS[2] + p0_.w*FS[3]   \
                   + p1_.x*FS[4] + p1_.y*FS[5] + p1_.z*FS[6] + p1_.w*FS[7];  \
    const int i_ = c * CH + ss * 2 + (E);                                    \
    if (i_ < NTOT) out[(size_t)i_ * 16u + k] = y_;                           \
    const float qv_[8] = {q0_.x,q0_.y,q0_.z,q0_.w,q1_.x,q1_.y,q1_.z,q1_.w};  \
    _Pragma("unroll") for (int mm = 0; mm < 8; ++mm) {                       \
      const float4 r0_ = *(const float4*)(agb + (E) * 256 + mm * 8);         \
      const float4 r1_ = *(const float4*)(agb + (E) * 256 + mm * 8 + 4);     \
      FD[mm] = qv_[mm] * xk_                                                 \
             + r0_.x*FS[0] + r0_.y*FS[1] + r0_.z*FS[2] + r0_.w*FS[3]         \
             + r1_.x*FS[4] + r1_.y*FS[5] + r1_.z*FS[6] + r1_.w*FS[7];        \
    }                                                                        \
  } while (0)

template<int NC>
__global__ __launch_bounds__(256, 4) void k3_output(
    const float* __restrict__ p, const float* __restrict__ q,
    const float* __restrict__ a, const float* __restrict__ x,
    const float* __restrict__ ws, float* __restrict__ out)
{
  using PP = P<NC>;
  constexpr int CH = PP::CH, NST = PP::NST;
  __shared__ float sm3[4 * 3 * 768];  // 36864 B
  const int wv   = (int)(threadIdx.x >> 6);
  const int wave = blockIdx.x * 4 + wv;
  const int lane = (int)(threadIdx.x & 63);
  const int g    = lane >> 4;
  const int k    = lane & 15;
  const int c    = wave * 4 + g;
  const int gr   = c >> 6;
  const int sidx = gr >> 6;

  const int cb = wave * 4;
  float* b0 = sm3 + wv * 2304;
  float* b1 = b0 + 768;
  float* b2 = b0 + 1536;

  const int goff = g * 64;
  const int qoff = 512 + g * 16;
  const int poff = 576 + g * 16;
  const int xoff = 640 + (g >> 1) * 64 + (g & 1) * 32 + k;

  auto stage = [&](int ss, float* lb) {          // 6 loads
    const int base = cb * CH + ss * 2;
    GLOAD_LDS16(a + (size_t)iminc(base + (lane >> 4) * CH,     NTOT - 1) * 64u + (lane & 15) * 4, lb);
    GLOAD_LDS16(a + (size_t)iminc(base + (lane >> 4) * CH + 1, NTOT - 1) * 64u + (lane & 15) * 4, lb + 256);
    GLOAD_LDS4 (q + (size_t)iminc(base + (lane >> 4) * CH + ((lane >> 3) & 1), NTOT - 1) * 8u  + (lane & 7),  lb + 512);
    GLOAD_LDS4 (p + (size_t)iminc(base + (lane >> 4) * CH + ((lane >> 3) & 1), NTOT - 1) * 8u  + (lane & 7),  lb + 576);
    GLOAD_LDS4 (x + (size_t)iminc(base + (lane >> 5) * CH + ((lane >> 4) & 1), NTOT - 1) * 16u + (lane & 15), lb + 640);
    GLOAD_LDS4 (x + (size_t)iminc(base + (2 + (lane >> 5)) * CH + ((lane >> 4) & 1), NTOT - 1) * 16u + (lane & 15), lb + 704);
  };

  stage(0, b0);   // issue first; f-init hides under the loads
  stage(1, b1);

  // f-init: t1 = gB_gr[:,k] + gA_gr @ sB_s[:,k]; f0 = prefB_c[:,k] + prefA_c @ t1
  const float* __restrict__ sBc = ws + PP::SGB  + (size_t)sidx * 128u + (size_t)k * 8u;
  const float* __restrict__ gBc = ws + PP::GAGB + (size_t)gr   * 128u + (size_t)k * 8u;
  const float* __restrict__ gA  = ws + PP::GAGA + (size_t)gr   * 64u;
  const float* __restrict__ pA  = ws + PP::AGGA + (size_t)c    * 64u;
  const float* __restrict__ lBc = ws + PP::AGGB + (size_t)c    * 128u + (size_t)k * 8u;
  float t1[8];
#pragma unroll
  for (int m = 0; m < 8; ++m) t1[m] = gBc[m];
#pragma unroll
  for (int t = 0; t < 8; ++t) {
    float4 c0 = *(const float4*)(gA + t * 8);
    float4 c1 = *(const float4*)(gA + t * 8 + 4);
    const float st = sBc[t];
    t1[0] += c0.x * st; t1[1] += c0.y * st; t1[2] += c0.z * st; t1[3] += c0.w * st;
    t1[4] += c1.x * st; t1[5] += c1.y * st; t1[6] += c1.z * st; t1[7] += c1.w * st;
  }
  float f0[8], f1[8];
#pragma unroll
  for (int m = 0; m < 8; ++m) f0[m] = lBc[m];
#pragma unroll
  for (int t = 0; t < 8; ++t) {
    float4 c0 = *(const float4*)(pA + t * 8);
    float4 c1 = *(const float4*)(pA + t * 8 + 4);
    const float gt = t1[t];
    f0[0] += c0.x * gt; f0[1] += c0.y * gt; f0[2] += c0.z * gt; f0[3] += c0.w * gt;
    f0[4] += c1.x * gt; f0[5] += c1.y * gt; f0[6] += c1.z * gt; f0[7] += c1.w * gt;
  }

#pragma unroll 1
  for (int ss = 0; ss < NST; ++ss) {
    float* lb = b0;
    if (ss + 2 < NST) {
      stage(ss + 2, b2);
      WAIT_VM(12);
    } else if (ss + 1 < NST) {
      WAIT_VM(6);
    } else {
      WAIT_VM(0);
    }
    const float* agb = lb + goff;
    const float* qgb = lb + qoff;
    const float* pgb = lb + poff;
    const float* xgb = lb + xoff;
    K3_COMP(0, f0, f1);
    K3_COMP(1, f1, f0);
    float* t = b0; b0 = b1; b1 = b2; b2 = t;
  }
}

template<int NC>
static void launch_all(const float* p, const float* q, const float* a,
                       const float* x, float* out, float* ws, hipStream_t stream)
{
  using PP = P<NC>;
  hipLaunchKernelGGL(HIP_KERNEL_NAME(k1_aggregate<NC>), dim3(NC / 16), dim3(256), 0, stream, q, a, x, ws);
  hipLaunchKernelGGL(HIP_KERNEL_NAME(k2scan<NC, 0>),    dim3(PP::NG),  dim3(64),  0, stream, ws);
  hipLaunchKernelGGL(HIP_KERNEL_NAME(k2scan<NC, 1>),    dim3(PP::NS),  dim3(64),  0, stream, ws);
  hipLaunchKernelGGL(HIP_KERNEL_NAME(k2c_topscan<NC>),  dim3(1),       dim3(64),  0, stream, ws);
  hipLaunchKernelGGL(HIP_KERNEL_NAME(k3_output<NC>),    dim3(NC / 16), dim3(256), 0, stream, p, q, a, x, ws, out);
}

extern "C" void kernel_launch(void* const* d_in, const int* in_sizes, int n_in,
                              void* d_out, int out_size, void* d_ws, size_t ws_size,
                              hipStream_t stream)
{
  const float* p = (const float*)d_in[0];
  const float* q = (const float*)d_in[1];
  const float* a = (const float*)d_in[2];
  const float* x = (const float*)d_in[3];
  float* out = (float*)d_out;
  float* ws  = (float*)d_ws;

  if (ws_size >= P<16384>::BYTES) {
    launch_all<16384>(p, q, a, x, out, ws, stream);   // 4 waves/SIMD path
  } else {
    launch_all<8192>(p, q, a, x, out, ws, stream);    // fallback (fits 6.4 MB)
  }
}